// Round 1
// baseline (106.922 us; speedup 1.0000x reference)
//
#include <hip/hip_runtime.h>

#define BB 16
#define TT 2048
#define DD 256
#define CC 8
// rows = B*T = 32768. Block = 256 threads (4 waves); each wave owns 16 rows;
// block owns 64 rows; grid = 32768/64 = 512 blocks. All rows of a block share b.

__global__ __launch_bounds__(256) void lde_main(
    const float* __restrict__ x,        // [B*T, D]
    const float* __restrict__ centers,  // [C, D]
    const float* __restrict__ scale,    // [C]
    float* __restrict__ agg_out,        // d_out as accumulator [B][C][D], pre-zeroed
    float* __restrict__ asum_out)       // d_ws [B][C], pre-zeroed
{
    __shared__ __align__(16) float c_lds[CC * DD];      // 8 KB centers
    __shared__ float csq_lds[CC];
    __shared__ float s_lds[CC];
    __shared__ __align__(16) float a_lds[4][16][CC];    // 2 KB assignments
    __shared__ __align__(16) float agg_lds[CC * DD];    // 8 KB block partial
    __shared__ float asum_lds[CC];

    const int tid  = threadIdx.x;
    const int lane = tid & 63;
    const int wave = tid >> 6;

    // ---- stage centers + zero partials ----
    #pragma unroll
    for (int i = 0; i < 8; ++i) c_lds[tid + i * 256] = centers[tid + i * 256];
    #pragma unroll
    for (int i = 0; i < 8; ++i) agg_lds[tid + i * 256] = 0.f;
    if (tid < CC) { csq_lds[tid] = 0.f; s_lds[tid] = scale[tid]; asum_lds[tid] = 0.f; }
    __syncthreads();

    // ---- csq[c] = sum_d centers[c][d]^2 (32 threads per c, 8 elems each) ----
    {
        const int c  = tid >> 5;
        const int d0 = (tid & 31) * 8;
        float s = 0.f;
        #pragma unroll
        for (int k = 0; k < 8; ++k) { float v = c_lds[c * DD + d0 + k]; s += v * v; }
        atomicAdd(&csq_lds[c], s);
    }
    __syncthreads();

    // ---- Phase 1: assignments. 4 lanes per row, interleaved-d quarters ----
    const int row0 = blockIdx.x * 64 + wave * 16;  // wave's 16 rows
    const int q    = lane & 3;                     // d-quarter
    const int rloc = lane >> 2;                    // 0..15 local row
    const int row  = row0 + rloc;
    const float* xrow = x + (size_t)row * DD;

    float dots[CC];
    float xsq = 0.f;
    #pragma unroll
    for (int c = 0; c < CC; ++c) dots[c] = 0.f;

    // preload the lane's 64 d-elements (16 float4, interleaved: elem 16k + 4q)
    float4 xr[16];
    #pragma unroll
    for (int k = 0; k < 16; ++k)
        xr[k] = *reinterpret_cast<const float4*>(xrow + k * 16 + q * 4);

    #pragma unroll
    for (int k = 0; k < 16; ++k) {
        const float4 xv = xr[k];
        xsq += xv.x * xv.x + xv.y * xv.y + xv.z * xv.z + xv.w * xv.w;
        #pragma unroll
        for (int c = 0; c < CC; ++c) {
            const float4 cv = *reinterpret_cast<const float4*>(&c_lds[c * DD + k * 16 + q * 4]);
            dots[c] += xv.x * cv.x + xv.y * cv.y + xv.z * cv.z + xv.w * cv.w;
        }
    }

    // quad butterfly: sums over the 4 lanes of a row group
    xsq += __shfl_xor(xsq, 1);
    xsq += __shfl_xor(xsq, 2);
    #pragma unroll
    for (int c = 0; c < CC; ++c) {
        dots[c] += __shfl_xor(dots[c], 1);
        dots[c] += __shfl_xor(dots[c], 2);
    }

    // softmax over c (redundant in the 4 lanes of the group)
    float logits[CC];
    float m = -1e30f;
    #pragma unroll
    for (int c = 0; c < CC; ++c) {
        logits[c] = -s_lds[c] * (xsq - 2.f * dots[c] + csq_lds[c]);
        m = fmaxf(m, logits[c]);
    }
    float e[CC];
    float ssum = 0.f;
    #pragma unroll
    for (int c = 0; c < CC; ++c) { e[c] = __expf(logits[c] - m); ssum += e[c]; }
    const float inv = 1.0f / ssum;

    // lane q writes a[2q], a[2q+1] (static-index select; no runtime reg indexing)
    float a0 = (q == 0) ? e[0] : (q == 1) ? e[2] : (q == 2) ? e[4] : e[6];
    float a1 = (q == 0) ? e[1] : (q == 1) ? e[3] : (q == 2) ? e[5] : e[7];
    *reinterpret_cast<float2*>(&a_lds[wave][rloc][q * 2]) = make_float2(a0 * inv, a1 * inv);

    __syncthreads();  // a_lds visibility (conservative; also keeps waves in phase)

    // ---- Phase 2: aggregation. Lane owns d = 4*lane..+3; x re-read (L2-hot) ----
    float4 accv[CC];
    float  asum[CC];
    #pragma unroll
    for (int c = 0; c < CC; ++c) { accv[c] = make_float4(0.f, 0.f, 0.f, 0.f); asum[c] = 0.f; }

    const float* xbase = x + (size_t)row0 * DD;
    #pragma unroll 4
    for (int r = 0; r < 16; ++r) {
        const float4 xv  = *reinterpret_cast<const float4*>(xbase + r * DD + lane * 4);
        const float4 av0 = *reinterpret_cast<const float4*>(&a_lds[wave][r][0]);
        const float4 av1 = *reinterpret_cast<const float4*>(&a_lds[wave][r][4]);
        accv[0].x += av0.x * xv.x; accv[0].y += av0.x * xv.y; accv[0].z += av0.x * xv.z; accv[0].w += av0.x * xv.w;
        accv[1].x += av0.y * xv.x; accv[1].y += av0.y * xv.y; accv[1].z += av0.y * xv.z; accv[1].w += av0.y * xv.w;
        accv[2].x += av0.z * xv.x; accv[2].y += av0.z * xv.y; accv[2].z += av0.z * xv.z; accv[2].w += av0.z * xv.w;
        accv[3].x += av0.w * xv.x; accv[3].y += av0.w * xv.y; accv[3].z += av0.w * xv.z; accv[3].w += av0.w * xv.w;
        accv[4].x += av1.x * xv.x; accv[4].y += av1.x * xv.y; accv[4].z += av1.x * xv.z; accv[4].w += av1.x * xv.w;
        accv[5].x += av1.y * xv.x; accv[5].y += av1.y * xv.y; accv[5].z += av1.y * xv.z; accv[5].w += av1.y * xv.w;
        accv[6].x += av1.z * xv.x; accv[6].y += av1.z * xv.y; accv[6].z += av1.z * xv.z; accv[6].w += av1.z * xv.w;
        accv[7].x += av1.w * xv.x; accv[7].y += av1.w * xv.y; accv[7].z += av1.w * xv.z; accv[7].w += av1.w * xv.w;
        asum[0] += av0.x; asum[1] += av0.y; asum[2] += av0.z; asum[3] += av0.w;
        asum[4] += av1.x; asum[5] += av1.y; asum[6] += av1.z; asum[7] += av1.w;
    }

    // ---- block-level reduction in LDS ----
    #pragma unroll
    for (int c = 0; c < CC; ++c) {
        atomicAdd(&agg_lds[c * DD + lane * 4 + 0], accv[c].x);
        atomicAdd(&agg_lds[c * DD + lane * 4 + 1], accv[c].y);
        atomicAdd(&agg_lds[c * DD + lane * 4 + 2], accv[c].z);
        atomicAdd(&agg_lds[c * DD + lane * 4 + 3], accv[c].w);
    }
    if (lane == 0) {
        #pragma unroll
        for (int c = 0; c < CC; ++c) atomicAdd(&asum_lds[c], asum[c]);
    }
    __syncthreads();

    // ---- global accumulation (32 blocks per b -> 32 atomics per address) ----
    const int b = blockIdx.x >> 5;
    float* aggb = agg_out + b * (CC * DD);
    #pragma unroll
    for (int i = 0; i < 8; ++i)
        atomicAdd(&aggb[tid + i * 256], agg_lds[tid + i * 256]);
    if (tid < CC) atomicAdd(&asum_out[b * CC + tid], asum_lds[tid]);
}

// out[b,c,d] -= asum[b,c] * centers[c,d]
__global__ __launch_bounds__(256) void lde_finalize(
    float* __restrict__ out,
    const float* __restrict__ asum,
    const float* __restrict__ centers)
{
    const int i = blockIdx.x * 256 + threadIdx.x;   // 0..32767
    const int d = i & (DD - 1);
    const int c = (i >> 8) & (CC - 1);
    const int b = i >> 11;
    out[i] -= asum[b * CC + c] * centers[c * DD + d];
}

extern "C" void kernel_launch(void* const* d_in, const int* in_sizes, int n_in,
                              void* d_out, int out_size, void* d_ws, size_t ws_size,
                              hipStream_t stream)
{
    const float* x       = (const float*)d_in[0];
    const float* centers = (const float*)d_in[1];
    const float* scale   = (const float*)d_in[2];
    float* out  = (float*)d_out;
    float* asum = (float*)d_ws;   // B*C floats = 512 B

    hipMemsetAsync(d_out, 0, (size_t)out_size * sizeof(float), stream);
    hipMemsetAsync(d_ws, 0, (size_t)(BB * CC) * sizeof(float), stream);

    lde_main<<<512, 256, 0, stream>>>(x, centers, scale, out, asum);
    lde_finalize<<<128, 256, 0, stream>>>(out, asum, centers);
}

// Round 3
// 88.770 us; speedup vs baseline: 1.2045x; 1.2045x over previous
//
#include <hip/hip_runtime.h>
#include <stdint.h>
#include <stddef.h>

#define DD   256
#define CC   8
#define RPB  32           // rows per block
#define RPW  8            // rows per wave
#define XROW 264          // padded row stride in words (256 + 8) -> breaks bank alias
#define NBLK 1024         // 32768 rows / 32

// global_load_lds: per-lane global src (16B each), wave-uniform LDS base (+lane*16B)
#define GLOAD16(g, l) __builtin_amdgcn_global_load_lds(                      \
    (const __attribute__((address_space(1))) void*)(g),                      \
    (__attribute__((address_space(3))) void*)(l), 16, 0, 0)

__device__ __forceinline__ float dot4(float4 a, float4 b) {
  return a.x * b.x + a.y * b.y + a.z * b.z + a.w * b.w;
}

__global__ __launch_bounds__(256) void lde_main(
    const float* __restrict__ x,        // [32768, 256]
    const float* __restrict__ centers,  // [8, 256]
    const float* __restrict__ scale,    // [8]
    float* __restrict__ pa,             // ws: [NBLK][8][256] block partials of sum a*x
    float* __restrict__ pas)            // ws: [NBLK][8]      block partials of sum a
{
  __shared__ __align__(16) float x_lds[RPB * XROW];  // 33 KB, padded rows
  __shared__ __align__(16) float c_lds[CC * DD];     // 8 KB
  __shared__ __align__(16) float a_lds[RPB * CC];    // 1 KB  assignments

  const int tid  = threadIdx.x;
  const int lane = tid & 63;
  const int wave = tid >> 6;
  const int blk  = blockIdx.x;

  // scale -> regs (uniform address => scalar loads)
  float sv[CC];
  #pragma unroll
  for (int c = 0; c < CC; ++c) sv[c] = scale[c];

  // ---- stage x tile: each wave issues 8 direct-to-LDS row loads (1 KB each) ----
  {
    const int  lrow0 = wave * RPW;
    const long grow0 = (long)blk * RPB + lrow0;
    #pragma unroll
    for (int r = 0; r < RPW; ++r) {
      const float* g = x + (grow0 + r) * DD + lane * 4;      // per-lane 16B
      GLOAD16(g, &x_lds[(lrow0 + r) * XROW]);                // uniform base, linear fill
    }
  }

  // ---- stage centers: 512 float4 by 256 threads ----
  {
    const float4* cg = (const float4*)centers;
    float4* cl = (float4*)c_lds;
    cl[tid]       = cg[tid];
    cl[tid + 256] = cg[tid + 256];
  }

  asm volatile("s_waitcnt vmcnt(0)" ::: "memory");
  __syncthreads();

  // ---- csq[c]: lane handles c = lane>>3, its o-chunks; octet reduce + broadcast ----
  float cs = 0.f;
  {
    const int c = lane >> 3, oo = lane & 7;
    #pragma unroll
    for (int k = 0; k < 8; ++k) {
      float4 cv = *(const float4*)&c_lds[c * DD + k * 32 + oo * 4];
      cs += dot4(cv, cv);
    }
    cs += __shfl_xor(cs, 1);
    cs += __shfl_xor(cs, 2);
    cs += __shfl_xor(cs, 4);
  }
  float csqv[CC];
  #pragma unroll
  for (int c = 0; c < CC; ++c) csqv[c] = __shfl(cs, c * 8);

  // ---- Phase 1: assignments. 8 lanes per row; lane owns interleaved chunks k*32+o*4 ----
  const int o    = lane & 7;
  const int rl   = lane >> 3;
  const int lrow = wave * RPW + rl;
  {
    const float* xr = &x_lds[lrow * XROW];
    float dots[CC] = {0.f, 0.f, 0.f, 0.f, 0.f, 0.f, 0.f, 0.f};
    float xsq = 0.f;
    #pragma unroll
    for (int k = 0; k < 8; ++k) {
      float4 xv = *(const float4*)&xr[k * 32 + o * 4];
      xsq += dot4(xv, xv);
      #pragma unroll
      for (int c = 0; c < CC; ++c) {
        float4 cv = *(const float4*)&c_lds[c * DD + k * 32 + o * 4];
        dots[c] += dot4(xv, cv);
      }
    }
    xsq += __shfl_xor(xsq, 1);
    xsq += __shfl_xor(xsq, 2);
    xsq += __shfl_xor(xsq, 4);
    #pragma unroll
    for (int c = 0; c < CC; ++c) {
      dots[c] += __shfl_xor(dots[c], 1);
      dots[c] += __shfl_xor(dots[c], 2);
      dots[c] += __shfl_xor(dots[c], 4);
    }

    float lgt[CC], m = -1e30f;
    #pragma unroll
    for (int c = 0; c < CC; ++c) {
      lgt[c] = -sv[c] * (xsq - 2.f * dots[c] + csqv[c]);
      m = fmaxf(m, lgt[c]);
    }
    float e[CC], ssum = 0.f;
    #pragma unroll
    for (int c = 0; c < CC; ++c) { e[c] = __expf(lgt[c] - m); ssum += e[c]; }
    const float inv = 1.f / ssum;
    // lane o stores a[o] (static-index select, no scratch)
    float eo = (o == 0) ? e[0] : (o == 1) ? e[1] : (o == 2) ? e[2] : (o == 3) ? e[3]
             : (o == 4) ? e[4] : (o == 5) ? e[5] : (o == 6) ? e[6] : e[7];
    a_lds[lrow * CC + o] = eo * inv;   // bank = lane -> 2-way, free
  }
  __syncthreads();

  // ---- block a_sum partial (wave 0 only, tiny) ----
  if (wave == 0) {
    const int c = lane >> 3, oo = lane & 7;
    float s = 0.f;
    #pragma unroll
    for (int j = 0; j < 4; ++j) s += a_lds[(j * 8 + oo) * CC + c];
    s += __shfl_xor(s, 1);
    s += __shfl_xor(s, 2);
    s += __shfl_xor(s, 4);
    if (oo == 0) pas[blk * CC + c] = s;
  }

  // ---- Phase 2: aggregation. Wave w owns d = w*64 + lane exclusively (no atomics) ----
  {
    const int d = wave * 64 + lane;
    float acc[CC] = {0.f, 0.f, 0.f, 0.f, 0.f, 0.f, 0.f, 0.f};
    #pragma unroll
    for (int r = 0; r < RPB; ++r) {
      const float  xv = x_lds[r * XROW + d];              // bank (r*8+lane)%32 -> 2-way
      const float4 a0 = *(const float4*)&a_lds[r * CC];   // broadcast
      const float4 a1 = *(const float4*)&a_lds[r * CC + 4];
      acc[0] += a0.x * xv; acc[1] += a0.y * xv; acc[2] += a0.z * xv; acc[3] += a0.w * xv;
      acc[4] += a1.x * xv; acc[5] += a1.y * xv; acc[6] += a1.z * xv; acc[7] += a1.w * xv;
    }
    float* pab = pa + (size_t)blk * (CC * DD);
    #pragma unroll
    for (int c = 0; c < CC; ++c) pab[c * DD + d] = acc[c];  // 256B coalesced per instr
  }
}

// out[b,c,d] = sum_k pa[b*64+k][c][d] - (sum_k pas[b*64+k][c]) * centers[c][d]
__global__ __launch_bounds__(256) void lde_finalize(
    const float* __restrict__ pa,
    const float* __restrict__ pas,
    const float* __restrict__ centers,
    float* __restrict__ out)
{
  const int b    = blockIdx.x >> 3;   // 16
  const int c    = blockIdx.x & 7;    // 8
  const int d    = threadIdx.x;       // 256
  const int lane = threadIdx.x & 63;

  // a_sum over 64 block-partials: lane k reads one, full-wave butterfly
  float v = pas[(b * 64 + lane) * CC + c];
  v += __shfl_xor(v, 1);
  v += __shfl_xor(v, 2);
  v += __shfl_xor(v, 4);
  v += __shfl_xor(v, 8);
  v += __shfl_xor(v, 16);
  v += __shfl_xor(v, 32);

  float s = 0.f;
  #pragma unroll 8
  for (int k = 0; k < 64; ++k)
    s += pa[((size_t)(b * 64 + k) * CC + c) * DD + d];   // coalesced 1KB per instr

  out[(b * CC + c) * DD + d] = s - v * centers[c * DD + d];
}

extern "C" void kernel_launch(void* const* d_in, const int* in_sizes, int n_in,
                              void* d_out, int out_size, void* d_ws, size_t ws_size,
                              hipStream_t stream)
{
  const float* x       = (const float*)d_in[0];
  const float* centers = (const float*)d_in[1];
  const float* scale   = (const float*)d_in[2];
  float* out = (float*)d_out;

  float* pa  = (float*)d_ws;                       // 1024*8*256*4 = 8 MB
  float* pas = pa + (size_t)NBLK * CC * DD;        // 1024*8*4     = 32 KB

  lde_main<<<NBLK, 256, 0, stream>>>(x, centers, scale, pa, pas);
  lde_finalize<<<128, 256, 0, stream>>>(pa, pas, centers, out);
}

// Round 4
// 85.978 us; speedup vs baseline: 1.2436x; 1.0325x over previous
//
#include <hip/hip_runtime.h>
#include <stdint.h>
#include <stddef.h>

#define DD   256
#define CC   8
#define BB   16
#define RPB  64           // rows per block
#define NBLK 512          // 32768 / 64
#define KPB  32           // NBLK / BB  = partial sets per batch image
#define XROW 264          // padded LDS row stride (words)

// global_load_lds: per-lane global src (16B), wave-uniform LDS base (+lane*16B)
#define GLOAD16(g, l) __builtin_amdgcn_global_load_lds(                      \
    (const __attribute__((address_space(1))) void*)(g),                      \
    (__attribute__((address_space(3))) void*)(l), 16, 0, 0)

__device__ __forceinline__ float dot4(float4 a, float4 b) {
  return a.x * b.x + a.y * b.y + a.z * b.z + a.w * b.w;
}

__global__ __launch_bounds__(256) void lde_main(
    const float* __restrict__ x,        // [32768, 256]
    const float* __restrict__ centers,  // [8, 256]
    const float* __restrict__ scale,    // [8]
    float* __restrict__ pa,             // ws: [C][NBLK][D] block partials of sum a*x
    float* __restrict__ pas)            // ws: [C][NBLK]    block partials of sum a
{
  __shared__ __align__(16) float x_lds[RPB * XROW];  // 66 KB padded rows (reused for reduce)
  __shared__ __align__(16) float c_lds[CC * DD];     // 8 KB
  __shared__ __align__(16) float a_lds[RPB * CC];    // 2 KB

  const int tid  = threadIdx.x;
  const int lane = tid & 63;
  const int wave = tid >> 6;
  const int blk  = blockIdx.x;

  float sv[CC];
  #pragma unroll
  for (int c = 0; c < CC; ++c) sv[c] = scale[c];   // uniform -> scalar loads

  // ---- stage x tile: wave issues 16 direct-to-LDS row loads (1 KB each) ----
  {
    const int  lrow0 = wave * 16;
    const long grow0 = (long)blk * RPB + lrow0;
    #pragma unroll
    for (int r = 0; r < 16; ++r) {
      const float* g = x + (grow0 + r) * DD + lane * 4;
      GLOAD16(g, &x_lds[(lrow0 + r) * XROW]);
    }
  }
  // ---- stage centers ----
  {
    const float4* cg = (const float4*)centers;
    float4* cl = (float4*)c_lds;
    cl[tid]       = cg[tid];
    cl[tid + 256] = cg[tid + 256];
  }
  asm volatile("s_waitcnt vmcnt(0)" ::: "memory");
  __syncthreads();

  // ---- csq[c] = ||centers[c]||^2 : lane (c=lane>>3, oo=lane&7), octet butterfly ----
  float csqv[CC];
  {
    const int c = lane >> 3, oo = lane & 7;
    float cs = 0.f;
    #pragma unroll
    for (int k = 0; k < 8; ++k) {
      float4 cv = *(const float4*)&c_lds[c * DD + k * 32 + oo * 4];
      cs += dot4(cv, cv);
    }
    cs += __shfl_xor(cs, 1);
    cs += __shfl_xor(cs, 2);
    cs += __shfl_xor(cs, 4);
    #pragma unroll
    for (int cc = 0; cc < CC; ++cc) csqv[cc] = __shfl(cs, cc * 8);
  }

  // ---- Phase 1: 8 lanes/row, 2 rows/lane (each c-chunk read feeds 2 rows) ----
  {
    const int o  = lane & 7;
    const int rl = lane >> 3;
    const int r0 = wave * 16 + rl;      // rows r0 and r0+8
    const float* xr0 = &x_lds[r0 * XROW];
    const float* xr1 = &x_lds[(r0 + 8) * XROW];

    float d0[CC] = {0,0,0,0,0,0,0,0};
    float d1[CC] = {0,0,0,0,0,0,0,0};
    float xq0 = 0.f, xq1 = 0.f;
    #pragma unroll
    for (int k = 0; k < 8; ++k) {
      const float4 xv0 = *(const float4*)&xr0[k * 32 + o * 4];
      const float4 xv1 = *(const float4*)&xr1[k * 32 + o * 4];
      xq0 += dot4(xv0, xv0);
      xq1 += dot4(xv1, xv1);
      #pragma unroll
      for (int c = 0; c < CC; ++c) {
        const float4 cv = *(const float4*)&c_lds[c * DD + k * 32 + o * 4];
        d0[c] += dot4(xv0, cv);
        d1[c] += dot4(xv1, cv);
      }
    }
    xq0 += __shfl_xor(xq0, 1); xq0 += __shfl_xor(xq0, 2); xq0 += __shfl_xor(xq0, 4);
    xq1 += __shfl_xor(xq1, 1); xq1 += __shfl_xor(xq1, 2); xq1 += __shfl_xor(xq1, 4);
    #pragma unroll
    for (int c = 0; c < CC; ++c) {
      d0[c] += __shfl_xor(d0[c], 1); d0[c] += __shfl_xor(d0[c], 2); d0[c] += __shfl_xor(d0[c], 4);
      d1[c] += __shfl_xor(d1[c], 1); d1[c] += __shfl_xor(d1[c], 2); d1[c] += __shfl_xor(d1[c], 4);
    }

    // softmax row r0
    {
      float lgt[CC], m = -1e30f;
      #pragma unroll
      for (int c = 0; c < CC; ++c) { lgt[c] = -sv[c] * (xq0 - 2.f * d0[c] + csqv[c]); m = fmaxf(m, lgt[c]); }
      float e[CC], ssum = 0.f;
      #pragma unroll
      for (int c = 0; c < CC; ++c) { e[c] = __expf(lgt[c] - m); ssum += e[c]; }
      const float inv = 1.f / ssum;
      float eo = (o == 0) ? e[0] : (o == 1) ? e[1] : (o == 2) ? e[2] : (o == 3) ? e[3]
               : (o == 4) ? e[4] : (o == 5) ? e[5] : (o == 6) ? e[6] : e[7];
      a_lds[r0 * CC + o] = eo * inv;
    }
    // softmax row r0+8
    {
      float lgt[CC], m = -1e30f;
      #pragma unroll
      for (int c = 0; c < CC; ++c) { lgt[c] = -sv[c] * (xq1 - 2.f * d1[c] + csqv[c]); m = fmaxf(m, lgt[c]); }
      float e[CC], ssum = 0.f;
      #pragma unroll
      for (int c = 0; c < CC; ++c) { e[c] = __expf(lgt[c] - m); ssum += e[c]; }
      const float inv = 1.f / ssum;
      float eo = (o == 0) ? e[0] : (o == 1) ? e[1] : (o == 2) ? e[2] : (o == 3) ? e[3]
               : (o == 4) ? e[4] : (o == 5) ? e[5] : (o == 6) ? e[6] : e[7];
      a_lds[(r0 + 8) * CC + o] = eo * inv;
    }
  }
  __syncthreads();

  // ---- pas block partial (wave 0 only) ----
  if (wave == 0) {
    const int c = lane >> 3, oo = lane & 7;
    float s = 0.f;
    #pragma unroll
    for (int j = 0; j < 8; ++j) s += a_lds[(j * 8 + oo) * CC + c];
    s += __shfl_xor(s, 1);
    s += __shfl_xor(s, 2);
    s += __shfl_xor(s, 4);
    if (oo == 0) pas[c * NBLK + blk] = s;
  }

  // ---- Phase 2: wave w rows w*16..+15, lane owns float4 d-chunk; a via shfl ----
  float4 acc[CC];
  #pragma unroll
  for (int c = 0; c < CC; ++c) acc[c] = make_float4(0.f, 0.f, 0.f, 0.f);
  {
    // lane L holds a[wave*16 + (L>>2)][(L&3)*2 .. +1]
    const float2 av = *(const float2*)&a_lds[(wave * 16 + (lane >> 2)) * CC + (lane & 3) * 2];
    #pragma unroll
    for (int r = 0; r < 16; ++r) {
      const float4 xv = *(const float4*)&x_lds[(wave * 16 + r) * XROW + lane * 4];
      #pragma unroll
      for (int c = 0; c < CC; ++c) {
        const float a = __shfl((c & 1) ? av.y : av.x, r * 4 + (c >> 1));
        acc[c].x += a * xv.x; acc[c].y += a * xv.y; acc[c].z += a * xv.z; acc[c].w += a * xv.w;
      }
    }
  }
  __syncthreads();                       // everyone done reading x_lds

  // ---- cross-wave reduce (reuse x_lds) + global partial store ----
  float* p_lds = x_lds;                  // [4][C][D] floats = 32 KB
  #pragma unroll
  for (int c = 0; c < CC; ++c)
    *(float4*)&p_lds[(wave * CC + c) * DD + lane * 4] = acc[c];
  __syncthreads();
  {
    const int c = tid >> 5;              // 0..7
    const int g = tid & 31;
    #pragma unroll
    for (int h = 0; h < 2; ++h) {
      const int d4 = g + 32 * h;
      float4 s0 = *(const float4*)&p_lds[(0 * CC + c) * DD + d4 * 4];
      float4 s1 = *(const float4*)&p_lds[(1 * CC + c) * DD + d4 * 4];
      float4 s2 = *(const float4*)&p_lds[(2 * CC + c) * DD + d4 * 4];
      float4 s3 = *(const float4*)&p_lds[(3 * CC + c) * DD + d4 * 4];
      float4 s = make_float4(s0.x + s1.x + s2.x + s3.x, s0.y + s1.y + s2.y + s3.y,
                             s0.z + s1.z + s2.z + s3.z, s0.w + s1.w + s2.w + s3.w);
      *(float4*)&pa[((size_t)c * NBLK + blk) * DD + d4 * 4] = s;
    }
  }
}

// out[b,c,d] = sum_k pa[c][b*32+k][d] - (sum_k pas[c][b*32+k]) * centers[c][d]
__global__ __launch_bounds__(256) void lde_finalize(
    const float* __restrict__ pa,
    const float* __restrict__ pas,
    const float* __restrict__ centers,
    float* __restrict__ out)
{
  __shared__ __align__(16) float r_lds[4][DD];   // 4 KB
  const int b  = blockIdx.x >> 3;
  const int c  = blockIdx.x & 7;
  const int kq = threadIdx.x >> 6;     // 0..3 (wave id)
  const int d4 = threadIdx.x & 63;     // float4 index over D

  const float* base = pa + ((size_t)c * NBLK + b * KPB) * DD;
  float4 s = make_float4(0.f, 0.f, 0.f, 0.f);
  #pragma unroll
  for (int j = 0; j < 8; ++j) {
    const float4 v = *(const float4*)&base[(kq * 8 + j) * DD + d4 * 4];
    s.x += v.x; s.y += v.y; s.z += v.z; s.w += v.w;
  }
  *(float4*)&r_lds[kq][d4 * 4] = s;
  __syncthreads();

  if (kq == 0) {   // wave 0 finishes
    float4 t0 = *(const float4*)&r_lds[0][d4 * 4];
    float4 t1 = *(const float4*)&r_lds[1][d4 * 4];
    float4 t2 = *(const float4*)&r_lds[2][d4 * 4];
    float4 t3 = *(const float4*)&r_lds[3][d4 * 4];
    float4 t = make_float4(t0.x + t1.x + t2.x + t3.x, t0.y + t1.y + t2.y + t3.y,
                           t0.z + t1.z + t2.z + t3.z, t0.w + t1.w + t2.w + t3.w);
    // a_sum: 32 partials, butterfly within 32-lane halves (both halves read same data)
    float v = pas[c * NBLK + b * KPB + (d4 & 31)];
    v += __shfl_xor(v, 1); v += __shfl_xor(v, 2); v += __shfl_xor(v, 4);
    v += __shfl_xor(v, 8); v += __shfl_xor(v, 16);
    const float4 cv = *(const float4*)&centers[c * DD + d4 * 4];
    float4 o4 = make_float4(t.x - v * cv.x, t.y - v * cv.y, t.z - v * cv.z, t.w - v * cv.w);
    *(float4*)&out[(size_t)(b * CC + c) * DD + d4 * 4] = o4;
  }
}

extern "C" void kernel_launch(void* const* d_in, const int* in_sizes, int n_in,
                              void* d_out, int out_size, void* d_ws, size_t ws_size,
                              hipStream_t stream)
{
  const float* x       = (const float*)d_in[0];
  const float* centers = (const float*)d_in[1];
  const float* scale   = (const float*)d_in[2];
  float* out = (float*)d_out;

  float* pa  = (float*)d_ws;                       // 8*512*256*4 = 4 MB
  float* pas = pa + (size_t)CC * NBLK * DD;        // 8*512*4     = 16 KB

  lde_main<<<NBLK, 256, 0, stream>>>(x, centers, scale, pa, pas);
  lde_finalize<<<BB * CC, 256, 0, stream>>>(pa, pas, centers, out);
}